// Round 14
// baseline (228.465 us; speedup 1.0000x reference)
//
#include <hip/hip_runtime.h>
#include <math.h>

// Problem constants (fixed by setup_inputs)
#define NQRY 8192   // queries
#define DIM  256    // d
#define MS   4608   // memory slots m
#define NQE  16384  // Nq embeddings
#define NBLK 8      // m // (C-1) partitions -> 8 blocks of 576
#define PRROWS 576

typedef __attribute__((ext_vector_type(8))) short bf16x8;
typedef __attribute__((ext_vector_type(4))) float f32x4;

// ---- d_out scratch layout (float offsets). All scratch is dead before
// k_read_mfma overwrites the entire output buffer. ----
// qh bf16    [8192][256]   @ 2,097,152
// ql bf16    [8192][256]   @ 3,145,728
// kh bf16    [4608][256]   @ 4,194,304
// kl bf16    [4608][256]   @ 4,784,128
// qu f32     [4608][256]   @ 5,373,952
// rowbest u64[8192]        @ 6,553,600
// colmax u32 [4608]        @ 6,569,984
// memr f32   [4608][256]   @ 6,574,592   (ends 7,754,240 < 67,108,864)
// ---- d_ws layout (bytes): ebT bf16 [2][16384][256] @ 0 (16 MB);
//      Gb bf16 [8][256][256] @ 16,777,216 (1 MB); sc f32[4] @ 17,825,792.

// async global->LDS, 16B/lane; LDS dest = wave-uniform base + lane*16
__device__ __forceinline__ void gl_lds16(const void* g, void* l) {
  __builtin_amdgcn_global_load_lds(
      (const __attribute__((address_space(1))) void*)g,
      (__attribute__((address_space(3))) void*)l, 16, 0, 0);
}

// Order-preserving float<->uint mapping for atomicMax on floats
__device__ __forceinline__ unsigned ordf(float f) {
  unsigned u = __float_as_uint(f);
  return (u & 0x80000000u) ? ~u : (u | 0x80000000u);
}
__device__ __forceinline__ float unordf(unsigned u) {
  unsigned b = (u & 0x80000000u) ? (u & 0x7FFFFFFFu) : ~u;
  return __uint_as_float(b);
}
// round-to-nearest-even f32 -> bf16 bits
__device__ __forceinline__ unsigned short bf16rn(float x) {
  unsigned u = __float_as_uint(x);
  unsigned r = u + 0x7FFFu + ((u >> 16) & 1u);
  return (unsigned short)(r >> 16);
}
// split: x = hi(bf16, trunc) + lo(bf16, RN); residual <= 2^-17 |x|
__device__ __forceinline__ void splitbf(float x, unsigned short& h, unsigned short& lo) {
  unsigned u = __float_as_uint(x);
  h = (unsigned short)(u >> 16);
  float hf = __uint_as_float(u & 0xFFFF0000u);
  lo = bf16rn(x - hf);
}

// K_prep: fused prep pipeline, role by blockIdx range (R7-proven):
// [0,8192) qnorm | [8192,12800) ksplit | [12800,16896) embt
// [16896,18069) zero qu+rowbest+colmax | 18069 scalars
#define PREP_NBLK 18070
#define ZERO_N4   300160
__global__ __launch_bounds__(256) void k_prep(
    const float* __restrict__ query,
    unsigned short* __restrict__ qh, unsigned short* __restrict__ ql,
    const float* __restrict__ keys,
    unsigned short* __restrict__ kh, unsigned short* __restrict__ kl,
    const float* __restrict__ embS, const float* __restrict__ embT,
    unsigned short* __restrict__ ebT,
    float4* __restrict__ zp,
    const int* __restrict__ labels, const float* __restrict__ cc,
    float* __restrict__ sc) {
  __shared__ float tile[64][33];
  int b = blockIdx.x, t = threadIdx.x;
  if (b < 8192) {
    // qnorm (q f32 not materialized; rowscatter reconstructs hi+lo)
    size_t idx = (size_t)b * DIM + t;
    float x = query[idx];
    float v = x * x;
    #pragma unroll
    for (int o = 32; o; o >>= 1) v += __shfl_down(v, o);
    float* s = &tile[0][0];
    if ((t & 63) == 0) s[t >> 6] = v;
    __syncthreads();
    float ss = (s[0] + s[1]) + (s[2] + s[3]);
    float qq = x / fmaxf(sqrtf(ss), 1e-12f);
    unsigned short h, lo;
    splitbf(qq, h, lo);
    qh[idx] = h; ql[idx] = lo;
  } else if (b < 12800) {
    // ksplit
    size_t idx = (size_t)(b - 8192) * 256 + t;
    unsigned short h, lo;
    splitbf(keys[idx], h, lo);
    kh[idx] = h; kl[idx] = lo;
  } else if (b < 16896) {
    // embt: transpose+convert emb [k][n] f32 -> ebT [n][k] bf16
    int bb = b - 12800;
    int x = bb & 511, y = (bb >> 9) & 3, z = bb >> 11;
    const float* emb = z ? embT : embS;
    int n0 = x * 32, k0 = y * 64;
    int kl2 = t >> 5, nl = t & 31;
    #pragma unroll
    for (int i = 0; i < 8; i++)
      tile[kl2 * 8 + i][nl] = emb[(size_t)(k0 + kl2 * 8 + i) * NQE + n0 + nl];
    __syncthreads();
    int nl2 = t >> 3, kq = (t & 7) * 8;
    bf16x8 hv;
    #pragma unroll
    for (int j = 0; j < 8; j++) hv[j] = (short)bf16rn(tile[kq + j][nl2]);
    *(bf16x8*)(ebT + (size_t)z * NQE * DIM + (size_t)(n0 + nl2) * DIM + k0 + kq) = hv;
  } else if (b < 18069) {
    // zero
    int i = (b - 16896) * 256 + t;
    if (i < ZERO_N4) zp[i] = float4{0.f, 0.f, 0.f, 0.f};
  } else {
    // scalars (wave 0 only)
    if (t < 64) {
      int l = (t < 16) ? labels[t] : (int)0x80000000;
      int mx = l;
      #pragma unroll
      for (int o = 32; o; o >>= 1) mx = max(mx, __shfl_down(mx, o));
      mx = __shfl(mx, 0);
      int cnt = (t < 16 && l == mx) ? 1 : 0;
      #pragma unroll
      for (int o = 32; o; o >>= 1) cnt += __shfl_down(cnt, o);
      unsigned amv = (t < 16) ? (1u << l) : 0u;
      #pragma unroll
      for (int o = 32; o; o >>= 1) amv |= __shfl_down(amv, o);
      if (t == 0) {
        sc[0] = __int_as_float(mx);
        sc[1] = (float)cnt;
        sc[2] = cc[mx];
        sc[3] = __uint_as_float(amv);
      }
    }
  }
}

// K4: score GEMM — gl_lds + double-buffer + DEFERRED vmcnt.
// Combination of two individually replay-verified mechanisms:
//  * gl_lds w16 staging, linear dest + inverse-swizzled source (R11/R12:
//    numerics validated, explicit vmcnt closes the R4 race);
//  * LDS double-buffer (R9: sync shape validated).
// Fix for both parents' losses: loads for tile kk+1 issue BEFORE the
// compute on tile kk, so the end-of-iteration vmcnt(0) waits on ~400-cycle
// old loads (near-zero stall, unlike R12's serial drain), and staging has
// no pf registers / ds_writes (unlike R9's reg-staged dbuf).
// WAR: buf[nxt]'s prior readers passed the previous iteration's barrier.
// RAW: explicit vmcnt(0) + __syncthreads before buf[nxt] is read.
__global__ __launch_bounds__(256) void k_scoremax(
    const unsigned short* __restrict__ qh, const unsigned short* __restrict__ ql,
    const unsigned short* __restrict__ kh, const unsigned short* __restrict__ kl,
    unsigned long long* __restrict__ rowbest, unsigned* __restrict__ colmax) {
  __shared__ __align__(16) char smem[65536];   // 2 x (sA 16K | sB 16K)
  int tid = threadIdx.x;
  int n0 = blockIdx.x * 128, m0 = blockIdx.y * 128;   // n: slots, m: queries
  int w = tid >> 6, lane = tid & 63;
  int wm = w >> 1, wn = w & 1;
  int lr = lane >> 4, lc = lane & 15;

  #define STAGE_SM(KK, BUF)                                                   \
    _Pragma("unroll")                                                         \
    for (int i = 0; i < 4; i++) {                                             \
      int c = w * 256 + i * 64 + lane;                                        \
      int row = c >> 3, ch = c & 7;                                           \
      int lch = ch ^ (row & 7);  /* logical chunk stored at this slot */      \
      gl_lds16(((lch < 4) ? qh : ql) +                                        \
                   (size_t)(m0 + row) * DIM + (KK) * 32 + (lch & 3) * 8,      \
               smem + (BUF) * 32768 + (w * 256 + i * 64) * 16);               \
      gl_lds16(((lch < 4) ? kh : kl) +                                        \
                   (size_t)(n0 + row) * DIM + (KK) * 32 + (lch & 3) * 8,      \
               smem + (BUF) * 32768 + 16384 + (w * 256 + i * 64) * 16);       \
    }

  STAGE_SM(0, 0);
  f32x4 acc[4][4] = {};
  asm volatile("s_waitcnt vmcnt(0)" ::: "memory");
  __syncthreads();

  for (int kk = 0; kk < 8; kk++) {
    char* sA = smem + (kk & 1) * 32768;
    char* sB = sA + 16384;
    if (kk < 7) { STAGE_SM(kk + 1, (kk + 1) & 1); }  // flies under compute
    bf16x8 ah[4], al[4];
    #pragma unroll
    for (int f = 0; f < 4; f++) {
      int ra = wm * 64 + f * 16 + lc;
      ah[f] = *(const bf16x8*)(sA + ra * 128 + ((lr ^ (ra & 7)) << 4));
      al[f] = *(const bf16x8*)(sA + ra * 128 + (((lr + 4) ^ (ra & 7)) << 4));
    }
    #pragma unroll
    for (int half = 0; half < 2; half++) {
      bf16x8 bh[2], bl[2];
      #pragma unroll
      for (int f2 = 0; f2 < 2; f2++) {
        int rb = wn * 64 + (half * 2 + f2) * 16 + lc;
        bh[f2] = *(const bf16x8*)(sB + rb * 128 + ((lr ^ (rb & 7)) << 4));
        bl[f2] = *(const bf16x8*)(sB + rb * 128 + (((lr + 4) ^ (rb & 7)) << 4));
      }
      #pragma unroll
      for (int fm = 0; fm < 4; fm++)
        #pragma unroll
        for (int f2 = 0; f2 < 2; f2++) {
          int fn = half * 2 + f2;
          acc[fm][fn] = __builtin_amdgcn_mfma_f32_16x16x32_bf16(ah[fm], bh[f2], acc[fm][fn], 0, 0, 0);
          acc[fm][fn] = __builtin_amdgcn_mfma_f32_16x16x32_bf16(ah[fm], bl[f2], acc[fm][fn], 0, 0, 0);
          acc[fm][fn] = __builtin_amdgcn_mfma_f32_16x16x32_bf16(al[fm], bh[f2], acc[fm][fn], 0, 0, 0);
        }
    }
    asm volatile("s_waitcnt vmcnt(0)" ::: "memory");  // kk+1 staged (old loads)
    __syncthreads();   // all waves done reading buf cur; buf nxt visible
  }
  #undef STAGE_SM
  // epilogue: row argmax (packed u64) + column max
  #pragma unroll
  for (int fm = 0; fm < 4; fm++) {
    #pragma unroll
    for (int rg = 0; rg < 4; rg++) {
      unsigned long long p = 0ull;
      #pragma unroll
      for (int fn = 0; fn < 4; fn++) {
        float v = acc[fm][fn][rg];
        unsigned ng = (unsigned)(n0 + wn * 64 + fn * 16 + lc);
        unsigned long long cand =
            ((unsigned long long)ordf(v) << 32) | (unsigned long long)(0xFFFFFFFFu - ng);
        if (cand > p) p = cand;
      }
      #pragma unroll
      for (int o = 1; o < 16; o <<= 1) {
        unsigned long long t2 = __shfl_xor(p, o);
        if (t2 > p) p = t2;
      }
      if (lc == 0)
        atomicMax(rowbest + (m0 + wm * 64 + fm * 16 + lr * 4 + rg), p);
    }
  }
  #pragma unroll
  for (int fn = 0; fn < 4; fn++) {
    float v = -3.4e38f;
    #pragma unroll
    for (int fm = 0; fm < 4; fm++)
      #pragma unroll
      for (int rg = 0; rg < 4; rg++) v = fmaxf(v, acc[fm][fn][rg]);
    v = fmaxf(v, __shfl_xor(v, 16));
    v = fmaxf(v, __shfl_xor(v, 32));
    if (lr == 0) atomicMax(colmax + (n0 + wn * 64 + fn * 16 + lc), ordf(v));
  }
}

// K5: per-query scatter; q reconstructed as hi+lo (err <= 2^-17, negligible).
__global__ __launch_bounds__(256) void k_rowscatter(
    const unsigned long long* __restrict__ rowbest, const unsigned* __restrict__ colmax,
    const unsigned short* __restrict__ qh, const unsigned short* __restrict__ ql,
    float* __restrict__ qu) {
  int i = blockIdx.x, t = threadIdx.x;
  unsigned long long p = rowbest[i];
  int g = (int)(0xFFFFFFFFu - (unsigned)(p & 0xFFFFFFFFull));
  float sv = unordf((unsigned)(p >> 32));
  float w = expf(sv - unordf(colmax[g]));
  size_t idx = (size_t)i * DIM + t;
  float qv = __uint_as_float((unsigned)qh[idx] << 16) +
             __uint_as_float((unsigned)ql[idx] << 16);
  atomicAdd(qu + (size_t)g * DIM + t, w * qv);
}

// K6: mem = l2norm((temp*keys + qu*active) / temp2)
__global__ __launch_bounds__(256) void k_mem(const float* __restrict__ keys,
                                             const float* __restrict__ qu,
                                             const float* __restrict__ sc,
                                             float* __restrict__ memr) {
  int j = blockIdx.x, t = threadIdx.x;
  int last = __float_as_int(sc[0]);
  float count = sc[1], ccl = sc[2];
  unsigned am = __float_as_uint(sc[3]);
  int cls = j >> 9;  // part = 512
  bool inp = (cls == last);
  float temp = inp ? ccl : 1.0f;
  float quv = ((am >> cls) & 1u) ? qu[(size_t)j * DIM + t] : 0.0f;
  float u = temp * keys[(size_t)j * DIM + t] + quv;
  float temp2 = temp + (inp ? count : 0.0f);
  float v = u / temp2;
  float vv = v * v;
  #pragma unroll
  for (int o = 32; o; o >>= 1) vv += __shfl_down(vv, o);
  __shared__ float s[4];
  if ((t & 63) == 0) s[t >> 6] = vv;
  __syncthreads();
  float ss = (s[0] + s[1]) + (s[2] + s[3]);
  memr[(size_t)j * DIM + t] = v / fmaxf(sqrtf(ss), 1e-12f);
}

// K7: G_b = B_b^T B_b (f32 vector compute), emit single bf16 (RN).
__global__ __launch_bounds__(256) void k_gram(const float* __restrict__ memr,
                                              unsigned short* __restrict__ Gb) {
  __shared__ float As[16][64];
  __shared__ float Bs[16][64];
  int b = blockIdx.z;
  int kxc = blockIdx.x * 64;
  int kyr = blockIdx.y * 64;
  const float* Ab = memr + (size_t)b * PRROWS * DIM;
  int tid = threadIdx.x, tx = tid & 15, ty = tid >> 4;
  int lp = tid >> 4;
  int lk = (tid & 15) * 4;
  float acc[4][4] = {};
  for (int p0 = 0; p0 < PRROWS; p0 += 16) {
    float4 av = *(const float4*)(Ab + (size_t)(p0 + lp) * DIM + kyr + lk);
    float4 bv = *(const float4*)(Ab + (size_t)(p0 + lp) * DIM + kxc + lk);
    __syncthreads();
    *(float4*)&As[lp][lk] = av;
    *(float4*)&Bs[lp][lk] = bv;
    __syncthreads();
    #pragma unroll
    for (int p = 0; p < 16; p++) {
      float a[4], c[4];
      *(float4*)&a[0] = *(const float4*)&As[p][ty * 4];
      *(float4*)&c[0] = *(const float4*)&Bs[p][tx * 4];
      #pragma unroll
      for (int r = 0; r < 4; r++)
        #pragma unroll
        for (int s2 = 0; s2 < 4; s2++)
          acc[r][s2] = fmaf(a[r], c[s2], acc[r][s2]);
    }
  }
  #pragma unroll
  for (int r = 0; r < 4; r++)
    #pragma unroll
    for (int s2 = 0; s2 < 4; s2++)
      Gb[(size_t)b * DIM * DIM + (size_t)(kyr + ty * 4 + r) * DIM + kxc + tx * 4 + s2] =
          bf16rn(acc[r][s2]);
}

// K8: out[eb][n][d] = ebT_e[n,:] @ G_b, 1-pass bf16 MFMA, reg-staged LDS
// with T14 reg-prefetch (R13 verbatim: best, replay-stable).
__global__ __launch_bounds__(256) void k_read_mfma(
    const unsigned short* __restrict__ ebT, const unsigned short* __restrict__ Gb,
    float* __restrict__ out) {
  __shared__ __align__(16) char smem[32768];
  char* sA = smem;
  char* sB = smem + 16384;
  int tid = threadIdx.x;
  int eb = blockIdx.z;
  const unsigned short* ea = ebT + (size_t)(eb >> 3) * NQE * DIM;
  const unsigned short* gb = Gb + (size_t)(eb & 7) * DIM * DIM;
  int n0 = blockIdx.x * 128, d0 = blockIdx.y * 128;
  int w = tid >> 6, l = tid & 63;
  int wm = w >> 1, wn = w & 1;
  int lr = l >> 4, lc = l & 15;
  bf16x8 pfa[4], pfb[4];
  #pragma unroll
  for (int t = 0; t < 4; t++) {
    int c = t * 256 + tid;
    int row = c >> 3, cc = c & 7;
    pfa[t] = *(const bf16x8*)(ea + (size_t)(n0 + row) * DIM + cc * 8);
    pfb[t] = *(const bf16x8*)(gb + (size_t)(d0 + row) * DIM + cc * 8);
  }
  f32x4 acc[4][4] = {};
  for (int kk = 0; kk < 4; kk++) {
    __syncthreads();
    #pragma unroll
    for (int t = 0; t < 4; t++) {
      int c = t * 256 + tid;
      int row = c >> 3, cc = c & 7;
      int ldsb = row * 128 + ((cc * 16) ^ ((row & 7) << 4));
      *(bf16x8*)(sA + ldsb) = pfa[t];
      *(bf16x8*)(sB + ldsb) = pfb[t];
    }
    __syncthreads();
    if (kk < 3) {
      #pragma unroll
      for (int t = 0; t < 4; t++) {
        int c = t * 256 + tid;
        int row = c >> 3, cc = c & 7;
        pfa[t] = *(const bf16x8*)(ea + (size_t)(n0 + row) * DIM + (kk + 1) * 64 + cc * 8);
        pfb[t] = *(const bf16x8*)(gb + (size_t)(d0 + row) * DIM + (kk + 1) * 64 + cc * 8);
      }
    }
    #pragma unroll
    for (int st = 0; st < 2; st++) {
      bf16x8 af[4], bf[4];
      #pragma unroll
      for (int f = 0; f < 4; f++) {
        int ra = wm * 64 + f * 16 + lc;
        int ka = (st * 64 + lr * 16) ^ ((ra & 7) << 4);
        af[f] = *(const bf16x8*)(sA + ra * 128 + ka);
        int rb = wn * 64 + f * 16 + lc;
        int kb = (st * 64 + lr * 16) ^ ((rb & 7) << 4);
        bf[f] = *(const bf16x8*)(sB + rb * 128 + kb);
      }
      #pragma unroll
      for (int fm = 0; fm < 4; fm++)
        #pragma unroll
        for (int fn = 0; fn < 4; fn++)
          acc[fm][fn] = __builtin_amdgcn_mfma_f32_16x16x32_bf16(af[fm], bf[fn], acc[fm][fn], 0, 0, 0);
    }
  }
  size_t base = (size_t)eb * NQE * DIM;
  #pragma unroll
  for (int fm = 0; fm < 4; fm++)
    #pragma unroll
    for (int rg = 0; rg < 4; rg++) {
      int n = n0 + wm * 64 + fm * 16 + lr * 4 + rg;
      float* op = out + base + (size_t)n * DIM + d0 + wn * 64 + lc;
      #pragma unroll
      for (int fn = 0; fn < 4; fn++) op[fn * 16] = acc[fm][fn][rg];
    }
}

extern "C" void kernel_launch(void* const* d_in, const int* in_sizes, int n_in,
                              void* d_out, int out_size, void* d_ws, size_t ws_size,
                              hipStream_t stream) {
  const float* query  = (const float*)d_in[0];
  const float* embS   = (const float*)d_in[1];
  const float* embT   = (const float*)d_in[2];
  const float* keys   = (const float*)d_in[3];
  const float* cc     = (const float*)d_in[4];
  const int*   labels = (const int*)d_in[5];
  float* out = (float*)d_out;

  unsigned short* qh           = (unsigned short*)(out + 2097152);
  unsigned short* ql           = (unsigned short*)(out + 3145728);
  unsigned short* kh           = (unsigned short*)(out + 4194304);
  unsigned short* kl           = (unsigned short*)(out + 4784128);
  float* qu                    = out + 5373952;
  unsigned long long* rowbest  = (unsigned long long*)(out + 6553600);
  unsigned* colmax             = (unsigned*)(out + 6569984);
  float* memr                  = out + 6574592;

  unsigned short* ebT = (unsigned short*)d_ws;                         // 16 MB
  unsigned short* Gb  = (unsigned short*)((char*)d_ws + 16777216);     // 1 MB
  float* sc           = (float*)((char*)d_ws + 17825792);              // 16 B

  k_prep<<<PREP_NBLK, 256, 0, stream>>>(query, qh, ql, keys, kh, kl,
                                        embS, embT, ebT, (float4*)qu,
                                        labels, cc, sc);
  k_scoremax<<<dim3(MS / 128, NQRY / 128), 256, 0, stream>>>(qh, ql, kh, kl, rowbest, colmax);
  k_rowscatter<<<NQRY, 256, 0, stream>>>(rowbest, colmax, qh, ql, qu);
  k_mem<<<MS, 256, 0, stream>>>(keys, qu, sc, memr);
  k_gram<<<dim3(4, 4, NBLK), 256, 0, stream>>>(memr, Gb);
  k_read_mfma<<<dim3(NQE / 128, DIM / 128, 2 * NBLK), 256, 0, stream>>>(ebT, Gb, out);
}

// Round 15
// 225.951 us; speedup vs baseline: 1.0111x; 1.0111x over previous
//
#include <hip/hip_runtime.h>
#include <math.h>

// Problem constants (fixed by setup_inputs)
#define NQRY 8192   // queries
#define DIM  256    // d
#define MS   4608   // memory slots m
#define NQE  16384  // Nq embeddings
#define NBLK 8      // m // (C-1) partitions -> 8 blocks of 576
#define PRROWS 576

typedef __attribute__((ext_vector_type(8))) short bf16x8;
typedef __attribute__((ext_vector_type(4))) float f32x4;

// ---- d_out scratch layout (float offsets). All scratch is dead before
// k_read_mfma overwrites the entire output buffer. ----
// qh bf16    [8192][256]   @ 2,097,152
// ql bf16    [8192][256]   @ 3,145,728
// kh bf16    [4608][256]   @ 4,194,304
// kl bf16    [4608][256]   @ 4,784,128
// qu f32     [4608][256]   @ 5,373,952
// rowbest u64[8192]        @ 6,553,600
// colmax u32 [4608]        @ 6,569,984
// memr f32   [4608][256]   @ 6,574,592   (ends 7,754,240 < 67,108,864)
// ---- d_ws layout (bytes): ebT bf16 [2][16384][256] @ 0 (16 MB);
//      Gb bf16 [8][256][256] @ 16,777,216 (1 MB); sc f32[4] @ 17,825,792.

// Order-preserving float<->uint mapping for atomicMax on floats
__device__ __forceinline__ unsigned ordf(float f) {
  unsigned u = __float_as_uint(f);
  return (u & 0x80000000u) ? ~u : (u | 0x80000000u);
}
__device__ __forceinline__ float unordf(unsigned u) {
  unsigned b = (u & 0x80000000u) ? (u & 0x7FFFFFFFu) : ~u;
  return __uint_as_float(b);
}
// round-to-nearest-even f32 -> bf16 bits
__device__ __forceinline__ unsigned short bf16rn(float x) {
  unsigned u = __float_as_uint(x);
  unsigned r = u + 0x7FFFu + ((u >> 16) & 1u);
  return (unsigned short)(r >> 16);
}
// split: x = hi(bf16, trunc) + lo(bf16, RN); residual <= 2^-17 |x|
__device__ __forceinline__ void splitbf(float x, unsigned short& h, unsigned short& lo) {
  unsigned u = __float_as_uint(x);
  h = (unsigned short)(u >> 16);
  float hf = __uint_as_float(u & 0xFFFF0000u);
  lo = bf16rn(x - hf);
}

// K_prep: fused prep pipeline, role by blockIdx range (R7-proven):
// [0,8192) qnorm | [8192,12800) ksplit | [12800,16896) embt
// [16896,18069) zero qu+rowbest+colmax | 18069 scalars
#define PREP_NBLK 18070
#define ZERO_N4   300160
__global__ __launch_bounds__(256) void k_prep(
    const float* __restrict__ query,
    unsigned short* __restrict__ qh, unsigned short* __restrict__ ql,
    const float* __restrict__ keys,
    unsigned short* __restrict__ kh, unsigned short* __restrict__ kl,
    const float* __restrict__ embS, const float* __restrict__ embT,
    unsigned short* __restrict__ ebT,
    float4* __restrict__ zp,
    const int* __restrict__ labels, const float* __restrict__ cc,
    float* __restrict__ sc) {
  __shared__ float tile[64][33];
  int b = blockIdx.x, t = threadIdx.x;
  if (b < 8192) {
    // qnorm (q f32 not materialized; rowscatter reconstructs hi+lo)
    size_t idx = (size_t)b * DIM + t;
    float x = query[idx];
    float v = x * x;
    #pragma unroll
    for (int o = 32; o; o >>= 1) v += __shfl_down(v, o);
    float* s = &tile[0][0];
    if ((t & 63) == 0) s[t >> 6] = v;
    __syncthreads();
    float ss = (s[0] + s[1]) + (s[2] + s[3]);
    float qq = x / fmaxf(sqrtf(ss), 1e-12f);
    unsigned short h, lo;
    splitbf(qq, h, lo);
    qh[idx] = h; ql[idx] = lo;
  } else if (b < 12800) {
    // ksplit
    size_t idx = (size_t)(b - 8192) * 256 + t;
    unsigned short h, lo;
    splitbf(keys[idx], h, lo);
    kh[idx] = h; kl[idx] = lo;
  } else if (b < 16896) {
    // embt: transpose+convert emb [k][n] f32 -> ebT [n][k] bf16
    int bb = b - 12800;
    int x = bb & 511, y = (bb >> 9) & 3, z = bb >> 11;
    const float* emb = z ? embT : embS;
    int n0 = x * 32, k0 = y * 64;
    int kl2 = t >> 5, nl = t & 31;
    #pragma unroll
    for (int i = 0; i < 8; i++)
      tile[kl2 * 8 + i][nl] = emb[(size_t)(k0 + kl2 * 8 + i) * NQE + n0 + nl];
    __syncthreads();
    int nl2 = t >> 3, kq = (t & 7) * 8;
    bf16x8 hv;
    #pragma unroll
    for (int j = 0; j < 8; j++) hv[j] = (short)bf16rn(tile[kq + j][nl2]);
    *(bf16x8*)(ebT + (size_t)z * NQE * DIM + (size_t)(n0 + nl2) * DIM + k0 + kq) = hv;
  } else if (b < 18069) {
    // zero
    int i = (b - 16896) * 256 + t;
    if (i < ZERO_N4) zp[i] = float4{0.f, 0.f, 0.f, 0.f};
  } else {
    // scalars (wave 0 only)
    if (t < 64) {
      int l = (t < 16) ? labels[t] : (int)0x80000000;
      int mx = l;
      #pragma unroll
      for (int o = 32; o; o >>= 1) mx = max(mx, __shfl_down(mx, o));
      mx = __shfl(mx, 0);
      int cnt = (t < 16 && l == mx) ? 1 : 0;
      #pragma unroll
      for (int o = 32; o; o >>= 1) cnt += __shfl_down(cnt, o);
      unsigned amv = (t < 16) ? (1u << l) : 0u;
      #pragma unroll
      for (int o = 32; o; o >>= 1) amv |= __shfl_down(amv, o);
      if (t == 0) {
        sc[0] = __int_as_float(mx);
        sc[1] = (float)cnt;
        sc[2] = cc[mx];
        sc[3] = __uint_as_float(amv);
      }
    }
  }
}

// K4: score GEMM — R8/R13-proven kernel (16x16x32 MFMA, BK=32 hi/lo
// interleaved 128B rows, XOR swizzle, 32KB LDS, 2-barrier + T14
// reg-prefetch; 5 staging restructures all lost to this form) with ONE
// addition: T1 chunked XCD swizzle. Default round-robin puts the 36
// blocks sharing an A-panel on 8 different XCDs (working set 13MB > 4MB
// L2 -> L3-served operand re-reads, ~590MB). Chunked transform gives
// XCD k the contiguous by-range [8k,8k+8): per-XCD working set 1MB A +
// 4.7MB B ~= L2-resident. Bijective: 2304 = 8 x 288. Pure index remap.
__global__ __launch_bounds__(256) void k_scoremax(
    const unsigned short* __restrict__ qh, const unsigned short* __restrict__ ql,
    const unsigned short* __restrict__ kh, const unsigned short* __restrict__ kl,
    unsigned long long* __restrict__ rowbest, unsigned* __restrict__ colmax) {
  __shared__ __align__(16) char smem[32768];
  char* sA = smem;
  char* sB = smem + 16384;
  int tid = threadIdx.x;
  // chunked XCD swizzle: dispatch round-robins bid%8 across XCDs, so give
  // each residue class one contiguous swz-chunk of 288 (= 8 by-rows).
  int bid = blockIdx.x;
  int swz = (bid & 7) * 288 + (bid >> 3);
  int bx = swz % 36, by = swz / 36;
  int n0 = bx * 128, m0 = by * 128;   // n: slots, m: queries
  int w = tid >> 6, lane = tid & 63;
  int wm = w >> 1, wn = w & 1;
  int lr = lane >> 4, lc = lane & 15;
  int srow = tid >> 3, sc8 = tid & 7;   // staging: row-slot 0..31, chunk 0..7
  bf16x8 pf[8];
  #pragma unroll
  for (int t = 0; t < 8; t++) {
    int row = (t & 3) * 32 + srow;
    const unsigned short* hsrc = (t < 4) ? qh : kh;
    const unsigned short* lsrc = (t < 4) ? ql : kl;
    int base = (t < 4) ? m0 : n0;
    pf[t] = *(const bf16x8*)(((sc8 < 4) ? hsrc : lsrc) +
                             (size_t)(base + row) * DIM + (sc8 & 3) * 8);
  }
  f32x4 acc[4][4] = {};
  for (int kk = 0; kk < 8; kk++) {
    __syncthreads();   // previous compute done reading LDS
    #pragma unroll
    for (int t = 0; t < 8; t++) {
      int row = (t & 3) * 32 + srow;
      char* dst = ((t < 4) ? sA : sB) + row * 128 + ((sc8 ^ (row & 7)) << 4);
      *(bf16x8*)dst = pf[t];
    }
    __syncthreads();
    if (kk < 7) {      // prefetch next K-tile (wave-uniform branch)
      #pragma unroll
      for (int t = 0; t < 8; t++) {
        int row = (t & 3) * 32 + srow;
        const unsigned short* hsrc = (t < 4) ? qh : kh;
        const unsigned short* lsrc = (t < 4) ? ql : kl;
        int base = (t < 4) ? m0 : n0;
        pf[t] = *(const bf16x8*)(((sc8 < 4) ? hsrc : lsrc) +
                                 (size_t)(base + row) * DIM + (kk + 1) * 32 + (sc8 & 3) * 8);
      }
    }
    bf16x8 ah[4], al[4];
    #pragma unroll
    for (int f = 0; f < 4; f++) {
      int ra = wm * 64 + f * 16 + lc;
      ah[f] = *(const bf16x8*)(sA + ra * 128 + ((lr ^ (ra & 7)) << 4));
      al[f] = *(const bf16x8*)(sA + ra * 128 + (((lr + 4) ^ (ra & 7)) << 4));
    }
    #pragma unroll
    for (int half = 0; half < 2; half++) {
      bf16x8 bh[2], bl[2];
      #pragma unroll
      for (int f2 = 0; f2 < 2; f2++) {
        int rb = wn * 64 + (half * 2 + f2) * 16 + lc;
        bh[f2] = *(const bf16x8*)(sB + rb * 128 + ((lr ^ (rb & 7)) << 4));
        bl[f2] = *(const bf16x8*)(sB + rb * 128 + (((lr + 4) ^ (rb & 7)) << 4));
      }
      #pragma unroll
      for (int fm = 0; fm < 4; fm++)
        #pragma unroll
        for (int f2 = 0; f2 < 2; f2++) {
          int fn = half * 2 + f2;
          acc[fm][fn] = __builtin_amdgcn_mfma_f32_16x16x32_bf16(ah[fm], bh[f2], acc[fm][fn], 0, 0, 0);
          acc[fm][fn] = __builtin_amdgcn_mfma_f32_16x16x32_bf16(ah[fm], bl[f2], acc[fm][fn], 0, 0, 0);
          acc[fm][fn] = __builtin_amdgcn_mfma_f32_16x16x32_bf16(al[fm], bh[f2], acc[fm][fn], 0, 0, 0);
        }
    }
  }
  // epilogue: row argmax (packed u64) + column max
  #pragma unroll
  for (int fm = 0; fm < 4; fm++) {
    #pragma unroll
    for (int rg = 0; rg < 4; rg++) {
      unsigned long long p = 0ull;
      #pragma unroll
      for (int fn = 0; fn < 4; fn++) {
        float v = acc[fm][fn][rg];
        unsigned ng = (unsigned)(n0 + wn * 64 + fn * 16 + lc);
        unsigned long long cand =
            ((unsigned long long)ordf(v) << 32) | (unsigned long long)(0xFFFFFFFFu - ng);
        if (cand > p) p = cand;
      }
      #pragma unroll
      for (int o = 1; o < 16; o <<= 1) {
        unsigned long long t2 = __shfl_xor(p, o);
        if (t2 > p) p = t2;
      }
      if (lc == 0)
        atomicMax(rowbest + (m0 + wm * 64 + fm * 16 + lr * 4 + rg), p);
    }
  }
  #pragma unroll
  for (int fn = 0; fn < 4; fn++) {
    float v = -3.4e38f;
    #pragma unroll
    for (int fm = 0; fm < 4; fm++)
      #pragma unroll
      for (int rg = 0; rg < 4; rg++) v = fmaxf(v, acc[fm][fn][rg]);
    v = fmaxf(v, __shfl_xor(v, 16));
    v = fmaxf(v, __shfl_xor(v, 32));
    if (lr == 0) atomicMax(colmax + (n0 + wn * 64 + fn * 16 + lc), ordf(v));
  }
}

// K5: per-query scatter; q reconstructed as hi+lo (err <= 2^-17, negligible).
__global__ __launch_bounds__(256) void k_rowscatter(
    const unsigned long long* __restrict__ rowbest, const unsigned* __restrict__ colmax,
    const unsigned short* __restrict__ qh, const unsigned short* __restrict__ ql,
    float* __restrict__ qu) {
  int i = blockIdx.x, t = threadIdx.x;
  unsigned long long p = rowbest[i];
  int g = (int)(0xFFFFFFFFu - (unsigned)(p & 0xFFFFFFFFull));
  float sv = unordf((unsigned)(p >> 32));
  float w = expf(sv - unordf(colmax[g]));
  size_t idx = (size_t)i * DIM + t;
  float qv = __uint_as_float((unsigned)qh[idx] << 16) +
             __uint_as_float((unsigned)ql[idx] << 16);
  atomicAdd(qu + (size_t)g * DIM + t, w * qv);
}

// K6: mem = l2norm((temp*keys + qu*active) / temp2)
__global__ __launch_bounds__(256) void k_mem(const float* __restrict__ keys,
                                             const float* __restrict__ qu,
                                             const float* __restrict__ sc,
                                             float* __restrict__ memr) {
  int j = blockIdx.x, t = threadIdx.x;
  int last = __float_as_int(sc[0]);
  float count = sc[1], ccl = sc[2];
  unsigned am = __float_as_uint(sc[3]);
  int cls = j >> 9;  // part = 512
  bool inp = (cls == last);
  float temp = inp ? ccl : 1.0f;
  float quv = ((am >> cls) & 1u) ? qu[(size_t)j * DIM + t] : 0.0f;
  float u = temp * keys[(size_t)j * DIM + t] + quv;
  float temp2 = temp + (inp ? count : 0.0f);
  float v = u / temp2;
  float vv = v * v;
  #pragma unroll
  for (int o = 32; o; o >>= 1) vv += __shfl_down(vv, o);
  __shared__ float s[4];
  if ((t & 63) == 0) s[t >> 6] = vv;
  __syncthreads();
  float ss = (s[0] + s[1]) + (s[2] + s[3]);
  memr[(size_t)j * DIM + t] = v / fmaxf(sqrtf(ss), 1e-12f);
}

// K7: G_b = B_b^T B_b (f32 vector compute), emit single bf16 (RN).
__global__ __launch_bounds__(256) void k_gram(const float* __restrict__ memr,
                                              unsigned short* __restrict__ Gb) {
  __shared__ float As[16][64];
  __shared__ float Bs[16][64];
  int b = blockIdx.z;
  int kxc = blockIdx.x * 64;
  int kyr = blockIdx.y * 64;
  const float* Ab = memr + (size_t)b * PRROWS * DIM;
  int tid = threadIdx.x, tx = tid & 15, ty = tid >> 4;
  int lp = tid >> 4;
  int lk = (tid & 15) * 4;
  float acc[4][4] = {};
  for (int p0 = 0; p0 < PRROWS; p0 += 16) {
    float4 av = *(const float4*)(Ab + (size_t)(p0 + lp) * DIM + kyr + lk);
    float4 bv = *(const float4*)(Ab + (size_t)(p0 + lp) * DIM + kxc + lk);
    __syncthreads();
    *(float4*)&As[lp][lk] = av;
    *(float4*)&Bs[lp][lk] = bv;
    __syncthreads();
    #pragma unroll
    for (int p = 0; p < 16; p++) {
      float a[4], c[4];
      *(float4*)&a[0] = *(const float4*)&As[p][ty * 4];
      *(float4*)&c[0] = *(const float4*)&Bs[p][tx * 4];
      #pragma unroll
      for (int r = 0; r < 4; r++)
        #pragma unroll
        for (int s2 = 0; s2 < 4; s2++)
          acc[r][s2] = fmaf(a[r], c[s2], acc[r][s2]);
    }
  }
  #pragma unroll
  for (int r = 0; r < 4; r++)
    #pragma unroll
    for (int s2 = 0; s2 < 4; s2++)
      Gb[(size_t)b * DIM * DIM + (size_t)(kyr + ty * 4 + r) * DIM + kxc + tx * 4 + s2] =
          bf16rn(acc[r][s2]);
}

// K8: out[eb][n][d] = ebT_e[n,:] @ G_b, 1-pass bf16 MFMA, reg-staged LDS
// with T14 reg-prefetch (R13 verbatim: best, replay-stable).
__global__ __launch_bounds__(256) void k_read_mfma(
    const unsigned short* __restrict__ ebT, const unsigned short* __restrict__ Gb,
    float* __restrict__ out) {
  __shared__ __align__(16) char smem[32768];
  char* sA = smem;
  char* sB = smem + 16384;
  int tid = threadIdx.x;
  int eb = blockIdx.z;
  const unsigned short* ea = ebT + (size_t)(eb >> 3) * NQE * DIM;
  const unsigned short* gb = Gb + (size_t)(eb & 7) * DIM * DIM;
  int n0 = blockIdx.x * 128, d0 = blockIdx.y * 128;
  int w = tid >> 6, l = tid & 63;
  int wm = w >> 1, wn = w & 1;
  int lr = l >> 4, lc = l & 15;
  bf16x8 pfa[4], pfb[4];
  #pragma unroll
  for (int t = 0; t < 4; t++) {
    int c = t * 256 + tid;
    int row = c >> 3, cc = c & 7;
    pfa[t] = *(const bf16x8*)(ea + (size_t)(n0 + row) * DIM + cc * 8);
    pfb[t] = *(const bf16x8*)(gb + (size_t)(d0 + row) * DIM + cc * 8);
  }
  f32x4 acc[4][4] = {};
  for (int kk = 0; kk < 4; kk++) {
    __syncthreads();
    #pragma unroll
    for (int t = 0; t < 4; t++) {
      int c = t * 256 + tid;
      int row = c >> 3, cc = c & 7;
      int ldsb = row * 128 + ((cc * 16) ^ ((row & 7) << 4));
      *(bf16x8*)(sA + ldsb) = pfa[t];
      *(bf16x8*)(sB + ldsb) = pfb[t];
    }
    __syncthreads();
    if (kk < 3) {
      #pragma unroll
      for (int t = 0; t < 4; t++) {
        int c = t * 256 + tid;
        int row = c >> 3, cc = c & 7;
        pfa[t] = *(const bf16x8*)(ea + (size_t)(n0 + row) * DIM + (kk + 1) * 64 + cc * 8);
        pfb[t] = *(const bf16x8*)(gb + (size_t)(d0 + row) * DIM + (kk + 1) * 64 + cc * 8);
      }
    }
    #pragma unroll
    for (int st = 0; st < 2; st++) {
      bf16x8 af[4], bf[4];
      #pragma unroll
      for (int f = 0; f < 4; f++) {
        int ra = wm * 64 + f * 16 + lc;
        int ka = (st * 64 + lr * 16) ^ ((ra & 7) << 4);
        af[f] = *(const bf16x8*)(sA + ra * 128 + ka);
        int rb = wn * 64 + f * 16 + lc;
        int kb = (st * 64 + lr * 16) ^ ((rb & 7) << 4);
        bf[f] = *(const bf16x8*)(sB + rb * 128 + kb);
      }
      #pragma unroll
      for (int fm = 0; fm < 4; fm++)
        #pragma unroll
        for (int fn = 0; fn < 4; fn++)
          acc[fm][fn] = __builtin_amdgcn_mfma_f32_16x16x32_bf16(af[fm], bf[fn], acc[fm][fn], 0, 0, 0);
    }
  }
  size_t base = (size_t)eb * NQE * DIM;
  #pragma unroll
  for (int fm = 0; fm < 4; fm++)
    #pragma unroll
    for (int rg = 0; rg < 4; rg++) {
      int n = n0 + wm * 64 + fm * 16 + lr * 4 + rg;
      float* op = out + base + (size_t)n * DIM + d0 + wn * 64 + lc;
      #pragma unroll
      for (int fn = 0; fn < 4; fn++) op[fn * 16] = acc[fm][fn][rg];
    }
}

extern "C" void kernel_launch(void* const* d_in, const int* in_sizes, int n_in,
                              void* d_out, int out_size, void* d_ws, size_t ws_size,
                              hipStream_t stream) {
  const float* query  = (const float*)d_in[0];
  const float* embS   = (const float*)d_in[1];
  const float* embT   = (const float*)d_in[2];
  const float* keys   = (const float*)d_in[3];
  const float* cc     = (const float*)d_in[4];
  const int*   labels = (const int*)d_in[5];
  float* out = (float*)d_out;

  unsigned short* qh           = (unsigned short*)(out + 2097152);
  unsigned short* ql           = (unsigned short*)(out + 3145728);
  unsigned short* kh           = (unsigned short*)(out + 4194304);
  unsigned short* kl           = (unsigned short*)(out + 4784128);
  float* qu                    = out + 5373952;
  unsigned long long* rowbest  = (unsigned long long*)(out + 6553600);
  unsigned* colmax             = (unsigned*)(out + 6569984);
  float* memr                  = out + 6574592;

  unsigned short* ebT = (unsigned short*)d_ws;                         // 16 MB
  unsigned short* Gb  = (unsigned short*)((char*)d_ws + 16777216);     // 1 MB
  float* sc           = (float*)((char*)d_ws + 17825792);              // 16 B

  k_prep<<<PREP_NBLK, 256, 0, stream>>>(query, qh, ql, keys, kh, kl,
                                        embS, embT, ebT, (float4*)qu,
                                        labels, cc, sc);
  k_scoremax<<<36 * 64, 256, 0, stream>>>(qh, ql, kh, kl, rowbest, colmax);
  k_rowscatter<<<NQRY, 256, 0, stream>>>(rowbest, colmax, qh, ql, qu);
  k_mem<<<MS, 256, 0, stream>>>(keys, qu, sc, memr);
  k_gram<<<dim3(4, 4, NBLK), 256, 0, stream>>>(memr, Gb);
  k_read_mfma<<<dim3(NQE / 128, DIM / 128, 2 * NBLK), 256, 0, stream>>>(ebT, Gb, out);
}

// Round 16
// 212.557 us; speedup vs baseline: 1.0748x; 1.0630x over previous
//
#include <hip/hip_runtime.h>
#include <math.h>

// Problem constants (fixed by setup_inputs)
#define NQRY 8192   // queries
#define DIM  256    // d
#define MS   4608   // memory slots m
#define NQE  16384  // Nq embeddings
#define NBLK 8      // m // (C-1) partitions -> 8 blocks of 576
#define PRROWS 576

typedef __attribute__((ext_vector_type(8))) short bf16x8;
typedef __attribute__((ext_vector_type(4))) float f32x4;

// ---- d_out scratch layout (float offsets). All scratch is dead before
// k_read_mfma overwrites the entire output buffer. ----
// qh bf16    [8192][256]   @ 2,097,152
// ql bf16    [8192][256]   @ 3,145,728
// kh bf16    [4608][256]   @ 4,194,304
// kl bf16    [4608][256]   @ 4,784,128
// qu f32     [4608][256]   @ 5,373,952
// rowbest u64[8192]        @ 6,553,600
// colmax u32 [4608]        @ 6,569,984
// memr f32   [4608][256]   @ 6,574,592   (ends 7,754,240 < 67,108,864)
// ---- d_ws layout (bytes): ebT bf16 [2][16384][256] @ 0 (16 MB);
//      Gb bf16 [8][256][256] @ 16,777,216 (1 MB); sc f32[4] @ 17,825,792.

// Order-preserving float<->uint mapping for atomicMax on floats
__device__ __forceinline__ unsigned ordf(float f) {
  unsigned u = __float_as_uint(f);
  return (u & 0x80000000u) ? ~u : (u | 0x80000000u);
}
__device__ __forceinline__ float unordf(unsigned u) {
  unsigned b = (u & 0x80000000u) ? (u & 0x7FFFFFFFu) : ~u;
  return __uint_as_float(b);
}
// round-to-nearest-even f32 -> bf16 bits
__device__ __forceinline__ unsigned short bf16rn(float x) {
  unsigned u = __float_as_uint(x);
  unsigned r = u + 0x7FFFu + ((u >> 16) & 1u);
  return (unsigned short)(r >> 16);
}
// split: x = hi(bf16, trunc) + lo(bf16, RN); residual <= 2^-17 |x|
__device__ __forceinline__ void splitbf(float x, unsigned short& h, unsigned short& lo) {
  unsigned u = __float_as_uint(x);
  h = (unsigned short)(u >> 16);
  float hf = __uint_as_float(u & 0xFFFF0000u);
  lo = bf16rn(x - hf);
}

// K_prep: fused prep pipeline, role by blockIdx range (R7-proven):
// [0,8192) qnorm | [8192,12800) ksplit | [12800,16896) embt
// [16896,18069) zero qu+rowbest+colmax | 18069 scalars
#define PREP_NBLK 18070
#define ZERO_N4   300160
__global__ __launch_bounds__(256) void k_prep(
    const float* __restrict__ query,
    unsigned short* __restrict__ qh, unsigned short* __restrict__ ql,
    const float* __restrict__ keys,
    unsigned short* __restrict__ kh, unsigned short* __restrict__ kl,
    const float* __restrict__ embS, const float* __restrict__ embT,
    unsigned short* __restrict__ ebT,
    float4* __restrict__ zp,
    const int* __restrict__ labels, const float* __restrict__ cc,
    float* __restrict__ sc) {
  __shared__ float tile[64][33];
  int b = blockIdx.x, t = threadIdx.x;
  if (b < 8192) {
    // qnorm (q f32 not materialized; rowscatter reconstructs hi+lo)
    size_t idx = (size_t)b * DIM + t;
    float x = query[idx];
    float v = x * x;
    #pragma unroll
    for (int o = 32; o; o >>= 1) v += __shfl_down(v, o);
    float* s = &tile[0][0];
    if ((t & 63) == 0) s[t >> 6] = v;
    __syncthreads();
    float ss = (s[0] + s[1]) + (s[2] + s[3]);
    float qq = x / fmaxf(sqrtf(ss), 1e-12f);
    unsigned short h, lo;
    splitbf(qq, h, lo);
    qh[idx] = h; ql[idx] = lo;
  } else if (b < 12800) {
    // ksplit
    size_t idx = (size_t)(b - 8192) * 256 + t;
    unsigned short h, lo;
    splitbf(keys[idx], h, lo);
    kh[idx] = h; kl[idx] = lo;
  } else if (b < 16896) {
    // embt: transpose+convert emb [k][n] f32 -> ebT [n][k] bf16
    int bb = b - 12800;
    int x = bb & 511, y = (bb >> 9) & 3, z = bb >> 11;
    const float* emb = z ? embT : embS;
    int n0 = x * 32, k0 = y * 64;
    int kl2 = t >> 5, nl = t & 31;
    #pragma unroll
    for (int i = 0; i < 8; i++)
      tile[kl2 * 8 + i][nl] = emb[(size_t)(k0 + kl2 * 8 + i) * NQE + n0 + nl];
    __syncthreads();
    int nl2 = t >> 3, kq = (t & 7) * 8;
    bf16x8 hv;
    #pragma unroll
    for (int j = 0; j < 8; j++) hv[j] = (short)bf16rn(tile[kq + j][nl2]);
    *(bf16x8*)(ebT + (size_t)z * NQE * DIM + (size_t)(n0 + nl2) * DIM + k0 + kq) = hv;
  } else if (b < 18069) {
    // zero
    int i = (b - 16896) * 256 + t;
    if (i < ZERO_N4) zp[i] = float4{0.f, 0.f, 0.f, 0.f};
  } else {
    // scalars (wave 0 only)
    if (t < 64) {
      int l = (t < 16) ? labels[t] : (int)0x80000000;
      int mx = l;
      #pragma unroll
      for (int o = 32; o; o >>= 1) mx = max(mx, __shfl_down(mx, o));
      mx = __shfl(mx, 0);
      int cnt = (t < 16 && l == mx) ? 1 : 0;
      #pragma unroll
      for (int o = 32; o; o >>= 1) cnt += __shfl_down(cnt, o);
      unsigned amv = (t < 16) ? (1u << l) : 0u;
      #pragma unroll
      for (int o = 32; o; o >>= 1) amv |= __shfl_down(amv, o);
      if (t == 0) {
        sc[0] = __int_as_float(mx);
        sc[1] = (float)cnt;
        sc[2] = cc[mx];
        sc[3] = __uint_as_float(amv);
      }
    }
  }
}

// K4: score GEMM — R8/R13-proven local optimum. 16x16x32 MFMA, BK=32 hi/lo
// interleaved 128B LDS rows, XOR-(row&7) swizzle, 32KB LDS, 2-barrier
// template + T14 reg-prefetch. Seven restructures (dbuf, A-direct, fenced
// gl_lds, drained gl_lds, combined dbuf+gl_lds, XCD swizzle) all lost to
// this form: every variant either halves occupancy (64KB LDS) or exposes
// global latency; wave-TLP at 3 blocks/CU beats all staged alternatives.
// XCD swizzle hurts because the 25MB working set is L3-fit (m160 lesson).
__global__ __launch_bounds__(256) void k_scoremax(
    const unsigned short* __restrict__ qh, const unsigned short* __restrict__ ql,
    const unsigned short* __restrict__ kh, const unsigned short* __restrict__ kl,
    unsigned long long* __restrict__ rowbest, unsigned* __restrict__ colmax) {
  __shared__ __align__(16) char smem[32768];
  char* sA = smem;
  char* sB = smem + 16384;
  int tid = threadIdx.x;
  int n0 = blockIdx.x * 128, m0 = blockIdx.y * 128;   // n: slots, m: queries
  int w = tid >> 6, lane = tid & 63;
  int wm = w >> 1, wn = w & 1;
  int lr = lane >> 4, lc = lane & 15;
  int srow = tid >> 3, sc8 = tid & 7;   // staging: row-slot 0..31, chunk 0..7
  bf16x8 pf[8];
  #pragma unroll
  for (int t = 0; t < 8; t++) {
    int row = (t & 3) * 32 + srow;
    const unsigned short* hsrc = (t < 4) ? qh : kh;
    const unsigned short* lsrc = (t < 4) ? ql : kl;
    int base = (t < 4) ? m0 : n0;
    pf[t] = *(const bf16x8*)(((sc8 < 4) ? hsrc : lsrc) +
                             (size_t)(base + row) * DIM + (sc8 & 3) * 8);
  }
  f32x4 acc[4][4] = {};
  for (int kk = 0; kk < 8; kk++) {
    __syncthreads();   // previous compute done reading LDS
    #pragma unroll
    for (int t = 0; t < 8; t++) {
      int row = (t & 3) * 32 + srow;
      char* dst = ((t < 4) ? sA : sB) + row * 128 + ((sc8 ^ (row & 7)) << 4);
      *(bf16x8*)dst = pf[t];
    }
    __syncthreads();
    if (kk < 7) {      // prefetch next K-tile (wave-uniform branch)
      #pragma unroll
      for (int t = 0; t < 8; t++) {
        int row = (t & 3) * 32 + srow;
        const unsigned short* hsrc = (t < 4) ? qh : kh;
        const unsigned short* lsrc = (t < 4) ? ql : kl;
        int base = (t < 4) ? m0 : n0;
        pf[t] = *(const bf16x8*)(((sc8 < 4) ? hsrc : lsrc) +
                                 (size_t)(base + row) * DIM + (kk + 1) * 32 + (sc8 & 3) * 8);
      }
    }
    bf16x8 ah[4], al[4];
    #pragma unroll
    for (int f = 0; f < 4; f++) {
      int ra = wm * 64 + f * 16 + lc;
      ah[f] = *(const bf16x8*)(sA + ra * 128 + ((lr ^ (ra & 7)) << 4));
      al[f] = *(const bf16x8*)(sA + ra * 128 + (((lr + 4) ^ (ra & 7)) << 4));
    }
    #pragma unroll
    for (int half = 0; half < 2; half++) {
      bf16x8 bh[2], bl[2];
      #pragma unroll
      for (int f2 = 0; f2 < 2; f2++) {
        int rb = wn * 64 + (half * 2 + f2) * 16 + lc;
        bh[f2] = *(const bf16x8*)(sB + rb * 128 + ((lr ^ (rb & 7)) << 4));
        bl[f2] = *(const bf16x8*)(sB + rb * 128 + (((lr + 4) ^ (rb & 7)) << 4));
      }
      #pragma unroll
      for (int fm = 0; fm < 4; fm++)
        #pragma unroll
        for (int f2 = 0; f2 < 2; f2++) {
          int fn = half * 2 + f2;
          acc[fm][fn] = __builtin_amdgcn_mfma_f32_16x16x32_bf16(ah[fm], bh[f2], acc[fm][fn], 0, 0, 0);
          acc[fm][fn] = __builtin_amdgcn_mfma_f32_16x16x32_bf16(ah[fm], bl[f2], acc[fm][fn], 0, 0, 0);
          acc[fm][fn] = __builtin_amdgcn_mfma_f32_16x16x32_bf16(al[fm], bh[f2], acc[fm][fn], 0, 0, 0);
        }
    }
  }
  // epilogue: row argmax (packed u64) + column max
  #pragma unroll
  for (int fm = 0; fm < 4; fm++) {
    #pragma unroll
    for (int rg = 0; rg < 4; rg++) {
      unsigned long long p = 0ull;
      #pragma unroll
      for (int fn = 0; fn < 4; fn++) {
        float v = acc[fm][fn][rg];
        unsigned ng = (unsigned)(n0 + wn * 64 + fn * 16 + lc);
        unsigned long long cand =
            ((unsigned long long)ordf(v) << 32) | (unsigned long long)(0xFFFFFFFFu - ng);
        if (cand > p) p = cand;
      }
      #pragma unroll
      for (int o = 1; o < 16; o <<= 1) {
        unsigned long long t2 = __shfl_xor(p, o);
        if (t2 > p) p = t2;
      }
      if (lc == 0)
        atomicMax(rowbest + (m0 + wm * 64 + fm * 16 + lr * 4 + rg), p);
    }
  }
  #pragma unroll
  for (int fn = 0; fn < 4; fn++) {
    float v = -3.4e38f;
    #pragma unroll
    for (int fm = 0; fm < 4; fm++)
      #pragma unroll
      for (int rg = 0; rg < 4; rg++) v = fmaxf(v, acc[fm][fn][rg]);
    v = fmaxf(v, __shfl_xor(v, 16));
    v = fmaxf(v, __shfl_xor(v, 32));
    if (lr == 0) atomicMax(colmax + (n0 + wn * 64 + fn * 16 + lc), ordf(v));
  }
}

// K5: per-query scatter; q reconstructed as hi+lo (err <= 2^-17, negligible).
__global__ __launch_bounds__(256) void k_rowscatter(
    const unsigned long long* __restrict__ rowbest, const unsigned* __restrict__ colmax,
    const unsigned short* __restrict__ qh, const unsigned short* __restrict__ ql,
    float* __restrict__ qu) {
  int i = blockIdx.x, t = threadIdx.x;
  unsigned long long p = rowbest[i];
  int g = (int)(0xFFFFFFFFu - (unsigned)(p & 0xFFFFFFFFull));
  float sv = unordf((unsigned)(p >> 32));
  float w = expf(sv - unordf(colmax[g]));
  size_t idx = (size_t)i * DIM + t;
  float qv = __uint_as_float((unsigned)qh[idx] << 16) +
             __uint_as_float((unsigned)ql[idx] << 16);
  atomicAdd(qu + (size_t)g * DIM + t, w * qv);
}

// K6: mem = l2norm((temp*keys + qu*active) / temp2)
__global__ __launch_bounds__(256) void k_mem(const float* __restrict__ keys,
                                             const float* __restrict__ qu,
                                             const float* __restrict__ sc,
                                             float* __restrict__ memr) {
  int j = blockIdx.x, t = threadIdx.x;
  int last = __float_as_int(sc[0]);
  float count = sc[1], ccl = sc[2];
  unsigned am = __float_as_uint(sc[3]);
  int cls = j >> 9;  // part = 512
  bool inp = (cls == last);
  float temp = inp ? ccl : 1.0f;
  float quv = ((am >> cls) & 1u) ? qu[(size_t)j * DIM + t] : 0.0f;
  float u = temp * keys[(size_t)j * DIM + t] + quv;
  float temp2 = temp + (inp ? count : 0.0f);
  float v = u / temp2;
  float vv = v * v;
  #pragma unroll
  for (int o = 32; o; o >>= 1) vv += __shfl_down(vv, o);
  __shared__ float s[4];
  if ((t & 63) == 0) s[t >> 6] = vv;
  __syncthreads();
  float ss = (s[0] + s[1]) + (s[2] + s[3]);
  memr[(size_t)j * DIM + t] = v / fmaxf(sqrtf(ss), 1e-12f);
}

// K7: G_b = B_b^T B_b (f32 vector compute), emit single bf16 (RN).
__global__ __launch_bounds__(256) void k_gram(const float* __restrict__ memr,
                                              unsigned short* __restrict__ Gb) {
  __shared__ float As[16][64];
  __shared__ float Bs[16][64];
  int b = blockIdx.z;
  int kxc = blockIdx.x * 64;
  int kyr = blockIdx.y * 64;
  const float* Ab = memr + (size_t)b * PRROWS * DIM;
  int tid = threadIdx.x, tx = tid & 15, ty = tid >> 4;
  int lp = tid >> 4;
  int lk = (tid & 15) * 4;
  float acc[4][4] = {};
  for (int p0 = 0; p0 < PRROWS; p0 += 16) {
    float4 av = *(const float4*)(Ab + (size_t)(p0 + lp) * DIM + kyr + lk);
    float4 bv = *(const float4*)(Ab + (size_t)(p0 + lp) * DIM + kxc + lk);
    __syncthreads();
    *(float4*)&As[lp][lk] = av;
    *(float4*)&Bs[lp][lk] = bv;
    __syncthreads();
    #pragma unroll
    for (int p = 0; p < 16; p++) {
      float a[4], c[4];
      *(float4*)&a[0] = *(const float4*)&As[p][ty * 4];
      *(float4*)&c[0] = *(const float4*)&Bs[p][tx * 4];
      #pragma unroll
      for (int r = 0; r < 4; r++)
        #pragma unroll
        for (int s2 = 0; s2 < 4; s2++)
          acc[r][s2] = fmaf(a[r], c[s2], acc[r][s2]);
    }
  }
  #pragma unroll
  for (int r = 0; r < 4; r++)
    #pragma unroll
    for (int s2 = 0; s2 < 4; s2++)
      Gb[(size_t)b * DIM * DIM + (size_t)(kyr + ty * 4 + r) * DIM + kxc + tx * 4 + s2] =
          bf16rn(acc[r][s2]);
}

// K8: out[eb][n][d] = ebT_e[n,:] @ G_b, 1-pass bf16 MFMA, reg-staged LDS
// with T14 reg-prefetch (R13 verbatim: best, replay-stable; at its 268MB
// HBM write floor).
__global__ __launch_bounds__(256) void k_read_mfma(
    const unsigned short* __restrict__ ebT, const unsigned short* __restrict__ Gb,
    float* __restrict__ out) {
  __shared__ __align__(16) char smem[32768];
  char* sA = smem;
  char* sB = smem + 16384;
  int tid = threadIdx.x;
  int eb = blockIdx.z;
  const unsigned short* ea = ebT + (size_t)(eb >> 3) * NQE * DIM;
  const unsigned short* gb = Gb + (size_t)(eb & 7) * DIM * DIM;
  int n0 = blockIdx.x * 128, d0 = blockIdx.y * 128;
  int w = tid >> 6, l = tid & 63;
  int wm = w >> 1, wn = w & 1;
  int lr = l >> 4, lc = l & 15;
  bf16x8 pfa[4], pfb[4];
  #pragma unroll
  for (int t = 0; t < 4; t++) {
    int c = t * 256 + tid;
    int row = c >> 3, cc = c & 7;
    pfa[t] = *(const bf16x8*)(ea + (size_t)(n0 + row) * DIM + cc * 8);
    pfb[t] = *(const bf16x8*)(gb + (size_t)(d0 + row) * DIM + cc * 8);
  }
  f32x4 acc[4][4] = {};
  for (int kk = 0; kk < 4; kk++) {
    __syncthreads();
    #pragma unroll
    for (int t = 0; t < 4; t++) {
      int c = t * 256 + tid;
      int row = c >> 3, cc = c & 7;
      int ldsb = row * 128 + ((cc * 16) ^ ((row & 7) << 4));
      *(bf16x8*)(sA + ldsb) = pfa[t];
      *(bf16x8*)(sB + ldsb) = pfb[t];
    }
    __syncthreads();
    if (kk < 3) {
      #pragma unroll
      for (int t = 0; t < 4; t++) {
        int c = t * 256 + tid;
        int row = c >> 3, cc = c & 7;
        pfa[t] = *(const bf16x8*)(ea + (size_t)(n0 + row) * DIM + (kk + 1) * 64 + cc * 8);
        pfb[t] = *(const bf16x8*)(gb + (size_t)(d0 + row) * DIM + (kk + 1) * 64 + cc * 8);
      }
    }
    #pragma unroll
    for (int st = 0; st < 2; st++) {
      bf16x8 af[4], bf[4];
      #pragma unroll
      for (int f = 0; f < 4; f++) {
        int ra = wm * 64 + f * 16 + lc;
        int ka = (st * 64 + lr * 16) ^ ((ra & 7) << 4);
        af[f] = *(const bf16x8*)(sA + ra * 128 + ka);
        int rb = wn * 64 + f * 16 + lc;
        int kb = (st * 64 + lr * 16) ^ ((rb & 7) << 4);
        bf[f] = *(const bf16x8*)(sB + rb * 128 + kb);
      }
      #pragma unroll
      for (int fm = 0; fm < 4; fm++)
        #pragma unroll
        for (int fn = 0; fn < 4; fn++)
          acc[fm][fn] = __builtin_amdgcn_mfma_f32_16x16x32_bf16(af[fm], bf[fn], acc[fm][fn], 0, 0, 0);
    }
  }
  size_t base = (size_t)eb * NQE * DIM;
  #pragma unroll
  for (int fm = 0; fm < 4; fm++)
    #pragma unroll
    for (int rg = 0; rg < 4; rg++) {
      int n = n0 + wm * 64 + fm * 16 + lr * 4 + rg;
      float* op = out + base + (size_t)n * DIM + d0 + wn * 64 + lc;
      #pragma unroll
      for (int fn = 0; fn < 4; fn++) op[fn * 16] = acc[fm][fn][rg];
    }
}

extern "C" void kernel_launch(void* const* d_in, const int* in_sizes, int n_in,
                              void* d_out, int out_size, void* d_ws, size_t ws_size,
                              hipStream_t stream) {
  const float* query  = (const float*)d_in[0];
  const float* embS   = (const float*)d_in[1];
  const float* embT   = (const float*)d_in[2];
  const float* keys   = (const float*)d_in[3];
  const float* cc     = (const float*)d_in[4];
  const int*   labels = (const int*)d_in[5];
  float* out = (float*)d_out;

  unsigned short* qh           = (unsigned short*)(out + 2097152);
  unsigned short* ql           = (unsigned short*)(out + 3145728);
  unsigned short* kh           = (unsigned short*)(out + 4194304);
  unsigned short* kl           = (unsigned short*)(out + 4784128);
  float* qu                    = out + 5373952;
  unsigned long long* rowbest  = (unsigned long long*)(out + 6553600);
  unsigned* colmax             = (unsigned*)(out + 6569984);
  float* memr                  = out + 6574592;

  unsigned short* ebT = (unsigned short*)d_ws;                         // 16 MB
  unsigned short* Gb  = (unsigned short*)((char*)d_ws + 16777216);     // 1 MB
  float* sc           = (float*)((char*)d_ws + 17825792);              // 16 B

  k_prep<<<PREP_NBLK, 256, 0, stream>>>(query, qh, ql, keys, kh, kl,
                                        embS, embT, ebT, (float4*)qu,
                                        labels, cc, sc);
  k_scoremax<<<dim3(MS / 128, NQRY / 128), 256, 0, stream>>>(qh, ql, kh, kl, rowbest, colmax);
  k_rowscatter<<<NQRY, 256, 0, stream>>>(rowbest, colmax, qh, ql, qu);
  k_mem<<<MS, 256, 0, stream>>>(keys, qu, sc, memr);
  k_gram<<<dim3(4, 4, NBLK), 256, 0, stream>>>(memr, Gb);
  k_read_mfma<<<dim3(NQE / 128, DIM / 128, 2 * NBLK), 256, 0, stream>>>(ebT, Gb, out);
}